// Round 1
// baseline (825.559 us; speedup 1.0000x reference)
//
#include <hip/hip_runtime.h>
#include <cstdint>
#include <cstddef>

typedef __bf16 bf16x8 __attribute__((ext_vector_type(8)));
typedef float f32x4 __attribute__((ext_vector_type(4)));

union V16 { uint4 u; bf16x8 b; unsigned short s[8]; };

__device__ __forceinline__ float b2f(unsigned short u) {
  unsigned int x = ((unsigned int)u) << 16;
  float f;
  __builtin_memcpy(&f, &x, 4);
  return f;
}
__device__ __forceinline__ unsigned short f2b(float f) {
  unsigned int u;
  __builtin_memcpy(&u, &f, 4);
  u = u + 0x7FFFu + ((u >> 16) & 1u);
  return (unsigned short)(u >> 16);
}

__device__ __forceinline__ f32x4 mfma16(bf16x8 a, bf16x8 b, f32x4 c) {
  return __builtin_amdgcn_mfma_f32_16x16x32_bf16(a, b, c, 0, 0, 0);
}

// async global->LDS, 16B per lane; LDS dest is wave-uniform base (+lane*16 implicit)
__device__ __forceinline__ void gld_lds16(const unsigned short* g, unsigned short* l) {
  __builtin_amdgcn_global_load_lds((__attribute__((address_space(1))) void*)g,
                                   (__attribute__((address_space(3))) void*)l,
                                   16, 0, 0);
}

// ---------------- merged f32 -> bf16 convert (all 7 weights, contiguous dst) ----------------
__global__ __launch_bounds__(256) void cvt_all(const float* __restrict__ wq,
                                               const float* __restrict__ wk,
                                               const float* __restrict__ wv,
                                               const float* __restrict__ wo,
                                               const float* __restrict__ wg,
                                               const float* __restrict__ wu,
                                               const float* __restrict__ wd,
                                               unsigned short* __restrict__ dst) {
  const int b = blockIdx.x;
  const float* src;
  if (b < 16384) {
    const int w = b >> 12;
    src = (w == 0 ? wq : w == 1 ? wk : w == 2 ? wv : wo) + (size_t)(b & 4095) * 1024;
  } else if (b < 32768) {
    src = wg + (size_t)(b - 16384) * 1024;
  } else if (b < 49152) {
    src = wu + (size_t)(b - 32768) * 1024;
  } else {
    src = wd + (size_t)(b - 49152) * 1024;
  }
  const int o = threadIdx.x * 4;
  const float4 v = *(const float4*)(src + o);
  ushort4 r;
  r.x = f2b(v.x); r.y = f2b(v.y); r.z = f2b(v.z); r.w = f2b(v.w);
  *(ushort4*)(dst + (size_t)b * 1024 + o) = r;
}

// ---------------- RMSNorm (f32 in -> bf16 out) ----------------
__global__ __launch_bounds__(256) void rms_k(const float* __restrict__ xin,
                                             const float* __restrict__ wgt,
                                             unsigned short* __restrict__ out) {
  const int s = blockIdx.x;
  const int t = threadIdx.x;
  float vals[8];
  float ss = 0.f;
#pragma unroll
  for (int i = 0; i < 8; ++i) {
    const int c = t + i * 256;
    const float f = xin[(size_t)s * 2048 + c];
    vals[i] = f;
    ss += f * f;
  }
#pragma unroll
  for (int off = 32; off > 0; off >>= 1) ss += __shfl_xor(ss, off);
  __shared__ float red[4];
  if ((t & 63) == 0) red[t >> 6] = ss;
  __syncthreads();
  ss = red[0] + red[1] + red[2] + red[3];
  const float sc = rsqrtf(ss * (1.f / 2048.f) + 1e-6f);
#pragma unroll
  for (int i = 0; i < 8; ++i) {
    const int c = t + i * 256;
    out[(size_t)s * 2048 + c] = f2b(vals[i] * sc * wgt[c]);
  }
}

// ---------------- RoPE (in-place bf16 q,k) + k^2*c precompute ----------------
__global__ __launch_bounds__(256) void rope_qk(unsigned short* qb, unsigned short* kb,
                                               const float* __restrict__ cosb,
                                               const float* __restrict__ sinb,
                                               float* __restrict__ k2c) {
  const int idx = blockIdx.x * 256 + threadIdx.x;  // 0 .. S*H*64
  const int d = idx & 63;
  const int h = (idx >> 6) & 15;
  const int s = idx >> 10;
  const size_t base = (size_t)s * 2048 + h * 128;
  const int cb = s * 128;
  const float c1 = cosb[cb + d],      s1 = sinb[cb + d];
  const float c2 = cosb[cb + d + 64], s2 = sinb[cb + d + 64];
  {
    const float x1 = b2f(qb[base + d]), x2 = b2f(qb[base + d + 64]);
    qb[base + d]      = f2b(x1 * c1 - x2 * s1);
    qb[base + d + 64] = f2b(x2 * c2 + x1 * s2);
  }
  {
    const float x1 = b2f(kb[base + d]), x2 = b2f(kb[base + d + 64]);
    const float k1 = x1 * c1 - x2 * s1;
    const float k2 = x2 * c2 + x1 * s2;
    kb[base + d]      = f2b(k1);
    kb[base + d + 64] = f2b(k2);
    float ss = k1 * k1 + k2 * k2;
#pragma unroll
    for (int off = 32; off > 0; off >>= 1) ss += __shfl_xor(ss, off);
    if (d == 0) k2c[h * 2048 + s] = ss * 0.04419417382415922f;
  }
}

// ---------------- NT GEMM (128-wide, m97 structure) -- kept for wo-proj only ----------------
// EPI 1: Cf[idx] = auxf[idx] + acc (f32 store)
template <int EPI, int RT>
__global__ __launch_bounds__(256, 2) void gemm_nt(
    const unsigned short* __restrict__ A,
    const unsigned short* __restrict__ B0,
    const unsigned short* __restrict__ B1,
    const unsigned short* __restrict__ B2,
    unsigned short* C0, unsigned short* C1, unsigned short* C2,
    const float* auxf, float* Cf,
    int N, int K, int kstride) {
  constexpr int TM = RT * 32;
  constexpr int APASS = TM / 64;
  const unsigned short* B;
  unsigned short* C;
  size_t koff = 0;
  if constexpr (EPI == 0) {
    B = (blockIdx.z == 0) ? B0 : (blockIdx.z == 1 ? B1 : B2);
    C = (blockIdx.z == 0) ? C0 : (blockIdx.z == 1 ? C1 : C2);
  } else {
    B = B0;
    C = C0;
    if constexpr (EPI == 3) koff = (size_t)blockIdx.z * K;
  }

  const int m0 = blockIdx.y * TM;
  const int n0 = blockIdx.x * 128;
  const int t = threadIdx.x;
  const int lane = t & 63;
  const int w = t >> 6;
  const int quad = lane >> 4;
  const int l15 = lane & 15;
  const int wr = w >> 1;
  const int wc = w & 1;

  __shared__ __align__(16) unsigned short As[TM * 32];
  __shared__ __align__(16) unsigned short Bs[128 * 32];

  const f32x4 vzero = {0.f, 0.f, 0.f, 0.f};
  f32x4 acc[RT][4];
#pragma unroll
  for (int i = 0; i < RT; ++i)
#pragma unroll
    for (int j = 0; j < 4; ++j) acc[i][j] = vzero;

  const int srow = w * 16 + (lane >> 2);
  const int scol = (lane & 3) * 8;
  const unsigned short* Ag = A + (size_t)(m0 + srow) * kstride + scol + koff;
  const unsigned short* Bg = B + (size_t)(n0 + srow) * kstride + scol + koff;

  for (int k0 = 0; k0 < K; k0 += 32) {
#pragma unroll
    for (int p = 0; p < APASS; ++p)
      gld_lds16(Ag + (size_t)p * 64 * kstride + k0, As + p * 2048 + w * 512);
#pragma unroll
    for (int p = 0; p < 2; ++p)
      gld_lds16(Bg + (size_t)p * 64 * kstride + k0, Bs + p * 2048 + w * 512);
    __syncthreads();

    bf16x8 af[RT], bfr[4];
#pragma unroll
    for (int rt = 0; rt < RT; ++rt)
      af[rt] = *(const bf16x8*)&As[(wr * (RT * 16) + rt * 16 + l15) * 32 + quad * 8];
#pragma unroll
    for (int ct = 0; ct < 4; ++ct)
      bfr[ct] = *(const bf16x8*)&Bs[(wc * 64 + ct * 16 + l15) * 32 + quad * 8];
#pragma unroll
    for (int rt = 0; rt < RT; ++rt)
#pragma unroll
      for (int ct = 0; ct < 4; ++ct)
        acc[rt][ct] = mfma16(af[rt], bfr[ct], acc[rt][ct]);
    __syncthreads();
  }

  float* Cfz = Cf;
  if constexpr (EPI == 3)
    Cfz = Cf + (size_t)blockIdx.z * (size_t)gridDim.y * TM * N;

#pragma unroll
  for (int rt = 0; rt < RT; ++rt) {
#pragma unroll
    for (int ct = 0; ct < 4; ++ct) {
#pragma unroll
      for (int r = 0; r < 4; ++r) {
        const int m = m0 + wr * (RT * 16) + rt * 16 + quad * 4 + r;
        const int n = n0 + wc * 64 + ct * 16 + l15;
        const size_t idx = (size_t)m * N + n;
        const float a = acc[rt][ct][r];
        if constexpr (EPI == 0) {
          C[idx] = f2b(a);
        } else if constexpr (EPI == 1) {
          Cf[idx] = auxf[idx] + a;
        } else {
          Cfz[idx] = a;
        }
      }
    }
  }
}

// ================= 256x256 8-phase NT GEMM (T2 swizzle + T3/T4 counted vmcnt + T5) ========
// C[M,N] = A[M,K] @ B[N,K]^T.  512 threads = 8 waves (2M x 4N), per-wave 128x64 output.
// BK=64. LDS 128 KiB: As/Bs[2 dbuf][2 half][128x64].
// Swizzle: LDS short (row, c) holds global (row, c ^ ((row&7)*8)) -- linear gld_lds dest,
// inverse-swizzled global source, swizzled ds_read (rule #21, involution both sides).
// Schedule per K-tile pair (8 phases): quadrants (mq,nq) = 00,01,10,11 per tile;
// phase 3/7 stage the NEXT tile for that buffer (issued 4 phases before first read)
// and wait counted vmcnt(8) for the OTHER buffer's in-flight stages.
#define BARRIER() asm volatile("s_barrier" ::: "memory")
#define WAITVM(N) asm volatile("s_waitcnt vmcnt(" #N ")" ::: "memory")
#define WAITLG()                                           \
  do {                                                     \
    asm volatile("s_waitcnt lgkmcnt(0)" ::: "memory");     \
    __builtin_amdgcn_sched_barrier(0);                     \
  } while (0)

#define LOADA(APT, MQ)                                                         \
  _Pragma("unroll") for (int j = 0; j < 4; ++j)                                \
  _Pragma("unroll") for (int ks = 0; ks < 2; ++ks)                             \
      afr[j][ks] = *(const bf16x8*)((APT) + ((MQ) * 64 + j * 16 + l15) * 64 +  \
                                    (ks ? ko1 : ko0));

#define LOADB(BPT, NQ)                                                         \
  _Pragma("unroll") for (int jn = 0; jn < 2; ++jn)                             \
  _Pragma("unroll") for (int ks = 0; ks < 2; ++ks)                             \
      bfr[(NQ) * 2 + jn][ks] =                                                 \
          *(const bf16x8*)((BPT) + ((NQ) * 32 + jn * 16 + l15) * 64 +          \
                           (ks ? ko1 : ko0));

#define MFMAQ(MQ, NQ)                                                          \
  do {                                                                         \
    __builtin_amdgcn_s_setprio(1);                                             \
    _Pragma("unroll") for (int j = 0; j < 4; ++j)                              \
    _Pragma("unroll") for (int jn = 0; jn < 2; ++jn)                           \
    _Pragma("unroll") for (int ks = 0; ks < 2; ++ks)                           \
        acc[(MQ) * 4 + j][(NQ) * 2 + jn] =                                     \
            mfma16(afr[j][ks], bfr[(NQ) * 2 + jn][ks],                         \
                   acc[(MQ) * 4 + j][(NQ) * 2 + jn]);                          \
    __builtin_amdgcn_s_setprio(0);                                             \
  } while (0)

// stage one full K-tile (A 256x64 + B 256x64) = 8 gld_lds16 per thread
#define STAGE8(DA, DB)                                                         \
  do {                                                                         \
    _Pragma("unroll") for (int h = 0; h < 2; ++h)                              \
    _Pragma("unroll") for (int i = 0; i < 2; ++i) {                            \
      gld_lds16(sAg + (size_t)(h * 128 + i * 64) * kstr,                       \
                (DA) + h * 8192 + i * 4096 + w * 512);                         \
      gld_lds16(sBg + (size_t)(h * 128 + i * 64) * kstr,                       \
                (DB) + h * 8192 + i * 4096 + w * 512);                         \
    }                                                                          \
    sAg += 64;                                                                 \
    sBg += 64;                                                                 \
  } while (0)

// 4 phases for one K-tile on (APT,BPT); STG/WTB = stage-next + counted-vmcnt hooks
#define TILEGRP(APT, BPT, STG, WTB)                                            \
  do {                                                                         \
    LOADA(APT, 0);                                                             \
    LOADB(BPT, 0);                                                             \
    BARRIER(); WAITLG(); MFMAQ(0, 0); BARRIER();                               \
    LOADB(BPT, 1);                                                             \
    BARRIER(); WAITLG(); MFMAQ(0, 1); BARRIER();                               \
    LOADA(APT, 1);                                                             \
    BARRIER(); WAITLG(); MFMAQ(1, 0); BARRIER();                               \
    STG;                                                                       \
    BARRIER(); MFMAQ(1, 1); WTB; BARRIER();                                    \
  } while (0)

// EPI 0: bf16 out split at n=8192 -> C0/C1 (gate+up).   EPI 1: bf16 3-way split at
// n=2048 -> C0/C1/C2 (QKV).   EPI 2: f32 split-K partial Cf + z*M*N, A/B offset z*Ktiles*64.
template <int EPI>
__global__ __launch_bounds__(512, 2) void gemm256(
    const unsigned short* __restrict__ A,
    const unsigned short* __restrict__ B,
    unsigned short* __restrict__ C0,
    unsigned short* __restrict__ C1,
    unsigned short* __restrict__ C2,
    float* __restrict__ Cf,
    int N, int kstr, int Ktiles) {
  // XCD-chunked block swizzle (bijective; all grids here are %8==0)
  const int gx = gridDim.x, gy = gridDim.y;
  const int nwg = gx * gy * gridDim.z;
  const int orig = blockIdx.x + gx * (blockIdx.y + gy * blockIdx.z);
  const int s = ((nwg & 7) == 0) ? ((orig & 7) * (nwg >> 3) + (orig >> 3)) : orig;
  const int bx = s % gx;
  const int sq = s / gx;
  const int by = sq % gy;
  const int bz = sq / gy;

  const int m0 = by * 256, n0 = bx * 256;
  const size_t koff = (size_t)bz * ((size_t)Ktiles * 64);

  const int t = threadIdx.x;
  const int lane = t & 63;
  const int w = t >> 6;
  const int quad = lane >> 4;
  const int l15 = lane & 15;
  const int wr = w >> 2;
  const int wc = w & 3;

  __shared__ __align__(16) unsigned short As[2][2][8192];
  __shared__ __align__(16) unsigned short Bs[2][2][8192];

  const f32x4 vzero = {0.f, 0.f, 0.f, 0.f};
  f32x4 acc[8][4];
#pragma unroll
  for (int i = 0; i < 8; ++i)
#pragma unroll
    for (int j = 0; j < 4; ++j) acc[i][j] = vzero;

  bf16x8 afr[4][2], bfr[4][2];

  // staging source (inverse-swizzled global col so linear gld_lds dest lands swizzled)
  const int lr = lane >> 3;                   // row-within-8 (== row&7 at dest)
  const int lc = ((lane & 7) ^ lr) * 8;       // swizzled source col (shorts)
  const unsigned short* sAg = A + (size_t)(m0 + w * 8 + lr) * kstr + koff + lc;
  const unsigned short* sBg = B + (size_t)(n0 + w * 8 + lr) * kstr + koff + lc;

  unsigned short* Asb0 = &As[0][0][0];
  unsigned short* Asb1 = &As[1][0][0];
  unsigned short* Bsb0 = &Bs[0][0][0];
  unsigned short* Bsb1 = &Bs[1][0][0];
  const unsigned short* Aw0 = &As[0][wr][0];
  const unsigned short* Aw1 = &As[1][wr][0];
  const unsigned short* Bw0 = &Bs[0][wc >> 1][0] + (wc & 1) * 4096;
  const unsigned short* Bw1 = &Bs[1][wc >> 1][0] + (wc & 1) * 4096;

  // swizzled ds_read col offsets (shorts) for ksub 0/1
  const int ax = (l15 & 7) * 8;
  const int ko0 = (quad * 8) ^ ax;
  const int ko1 = (32 + quad * 8) ^ ax;

  // prologue: tiles 0,1 in flight; wait tile0 (vmcnt leaves tile1's 8 outstanding)
  STAGE8(Asb0, Bsb0);
  STAGE8(Asb1, Bsb1);
  WAITVM(8);
  BARRIER();

  const int nIter = (Ktiles >> 1) - 1;
  for (int it = 0; it < nIter; ++it) {
    TILEGRP(Aw0, Bw0, STAGE8(Asb0, Bsb0), WAITVM(8));
    TILEGRP(Aw1, Bw1, STAGE8(Asb1, Bsb1), WAITVM(8));
  }
  TILEGRP(Aw0, Bw0, (void)0, WAITVM(0));
  TILEGRP(Aw1, Bw1, (void)0, (void)0);

  // ----- epilogue -----
  if constexpr (EPI == 2) {
    const size_t MN = (size_t)gy * 256 * N;
    float* Cp = Cf + (size_t)bz * MN;
#pragma unroll
    for (int mf = 0; mf < 8; ++mf) {
      const int m = m0 + wr * 128 + mf * 16 + quad * 4;
#pragma unroll
      for (int nf = 0; nf < 4; ++nf) {
        const int n = n0 + wc * 64 + nf * 16 + l15;
#pragma unroll
        for (int r = 0; r < 4; ++r) Cp[(size_t)(m + r) * N + n] = acc[mf][nf][r];
      }
    }
  } else {
    unsigned short* Cp;
    int nb;
    constexpr int ldc = (EPI == 0) ? 8192 : 2048;
    if constexpr (EPI == 0) {
      Cp = (n0 < 8192) ? C0 : C1;   // block-uniform (8192 % 256 == 0)
      nb = n0 & 8191;
    } else {
      const int wsel = n0 >> 11;    // block-uniform (2048 % 256 == 0)
      Cp = wsel == 0 ? C0 : (wsel == 1 ? C1 : C2);
      nb = n0 & 2047;
    }
#pragma unroll
    for (int mf = 0; mf < 8; ++mf) {
      const int m = m0 + wr * 128 + mf * 16 + quad * 4;
#pragma unroll
      for (int nf = 0; nf < 4; ++nf) {
        const int n = nb + wc * 64 + nf * 16 + l15;
#pragma unroll
        for (int r = 0; r < 4; ++r)
          Cp[(size_t)(m + r) * ldc + n] = f2b(acc[mf][nf][r]);
      }
    }
  }
}

// ---------------- silu(g)*u elementwise, in-place over g ----------------
__global__ __launch_bounds__(256) void silu_k(unsigned short* __restrict__ g,
                                              const unsigned short* __restrict__ u) {
  const size_t i = ((size_t)blockIdx.x * 256 + threadIdx.x) * 8;
  V16 gv, uv, ov;
  gv.u = *(const uint4*)(g + i);
  uv.u = *(const uint4*)(u + i);
#pragma unroll
  for (int e = 0; e < 8; ++e) {
    const float gf = b2f(gv.s[e]);
    const float uf = b2f(uv.s[e]);
    ov.s[e] = f2b(gf / (1.f + __expf(-gf)) * uf);
  }
  *(uint4*)(g + i) = ov.u;
}

// ---------------- split-K=4 combine: out = hf + p0+p1+p2+p3 ----------------
__global__ __launch_bounds__(256) void comb4(const float* __restrict__ p,
                                             const float* __restrict__ hf,
                                             float* __restrict__ out) {
  const size_t i = ((size_t)blockIdx.x * 256 + threadIdx.x) * 4;
  const size_t MN = (size_t)2048 * 2048;
  float4 a = *(const float4*)(p + i);
  const float4 b = *(const float4*)(p + MN + i);
  const float4 c = *(const float4*)(p + 2 * MN + i);
  const float4 d = *(const float4*)(p + 3 * MN + i);
  const float4 h = *(const float4*)(hf + i);
  a.x += b.x + c.x + d.x + h.x;
  a.y += b.y + c.y + d.y + h.y;
  a.z += b.z + c.z + d.z + h.z;
  a.w += b.w + c.w + d.w + h.w;
  *(float4*)(out + i) = a;
}

// ---------------- Flash W2 (Gaussian-kernel) attention ----------------
__global__ __launch_bounds__(256, 3) void flash_w2(
    const unsigned short* __restrict__ q,
    const unsigned short* __restrict__ kk,
    const unsigned short* __restrict__ v,
    const float* __restrict__ k2c,
    unsigned short* __restrict__ ctx) {
  constexpr int Cw = 2048;
  constexpr float TWOC = 0.08838834764831843f;  // 1/sqrt(128)
  const int h = blockIdx.y;
  const int i = (h >= 8) ? (31 - blockIdx.x) : blockIdx.x;
  const int i0 = i * 64;
  const int t = threadIdx.x;
  const int lane = t & 63;
  const int w = t >> 6;
  const int quad = lane >> 4;
  const int l15 = lane & 15;

  __shared__ __align__(16) unsigned short Ks[64 * 136];   // [j][d], pitch 136
  __shared__ __align__(16) unsigned short VTs[128 * 72];  // [d][j^], XOR-swizzled
  __shared__ __align__(16) unsigned short Ps[4][16 * 72]; // per-wave P

  bf16x8 aq[4];
  {
    const unsigned short* qp = q + (size_t)(i0 + w * 16 + l15) * Cw + h * 128;
#pragma unroll
    for (int kt = 0; kt < 4; ++kt) {
      V16 u;
      u.u = *(const uint4*)(qp + kt * 32 + quad * 8);
      aq[kt] = u.b;
    }
  }

  const f32x4 vzero = {0.f, 0.f, 0.f, 0.f};
  f32x4 o[8];
#pragma unroll
  for (int nt = 0; nt < 8; ++nt) o[nt] = vzero;
  float mrow[4] = {-1e30f, -1e30f, -1e30f, -1e30f};
  float lrow[4] = {0.f, 0.f, 0.f, 0.f};

  const int njt = i + 1;
  const int jr = t >> 2;
  const int c0 = (t & 3) * 32;
  const int jlo = jr & 7;
  const int jhi = jr >> 3;
  for (int jt = 0; jt < njt; ++jt) {
    const int j0 = jt * 64;
    __syncthreads();
    {
      const unsigned short* kp = kk + (size_t)(j0 + jr) * Cw + h * 128 + c0;
      const unsigned short* vp = v + (size_t)(j0 + jr) * Cw + h * 128 + c0;
#pragma unroll
      for (int ii = 0; ii < 4; ++ii) {
        *(uint4*)&Ks[jr * 136 + c0 + ii * 8] = *(const uint4*)(kp + ii * 8);
        V16 vu;
        vu.u = *(const uint4*)(vp + ii * 8);
#pragma unroll
        for (int e = 0; e < 8; ++e) {
          const int dd = c0 + ii * 8 + e;
          const int gs = (jhi ^ (dd >> 4)) & 7;
          VTs[dd * 72 + (jlo | (gs << 3))] = vu.s[e];
        }
      }
    }
    __syncthreads();

    float k2v[4];
#pragma unroll
    for (int ct = 0; ct < 4; ++ct) k2v[ct] = k2c[h * 2048 + j0 + ct * 16 + l15];

    f32x4 sc[4];
#pragma unroll
    for (int ct = 0; ct < 4; ++ct) {
      f32x4 a = vzero;
#pragma unroll
      for (int kt = 0; kt < 4; ++kt) {
        V16 u;
        u.u = *(const uint4*)&Ks[(ct * 16 + l15) * 136 + kt * 32 + quad * 8];
        a = mfma16(aq[kt], u.b, a);
      }
      sc[ct] = a;
    }

    const bool diag = (jt == njt - 1);
#pragma unroll
    for (int ct = 0; ct < 4; ++ct) {
#pragma unroll
      for (int r = 0; r < 4; ++r) {
        float s = fmaf(TWOC, sc[ct][r], -k2v[ct]);
        if (diag) {
          const int gi = w * 16 + quad * 4 + r;
          const int gj = ct * 16 + l15;
          s = (gj <= gi) ? s : -1e30f;
        }
        sc[ct][r] = s;
      }
    }

    float al[4];
#pragma unroll
    for (int r = 0; r < 4; ++r) {
      float rm = fmaxf(fmaxf(sc[0][r], sc[1][r]), fmaxf(sc[2][r], sc[3][r]));
      rm = fmaxf(rm, __shfl_xor(rm, 1));
      rm = fmaxf(rm, __shfl_xor(rm, 2));
      rm = fmaxf(rm, __shfl_xor(rm, 4));
      rm = fmaxf(rm, __shfl_xor(rm, 8));
      const float mn = fmaxf(mrow[r], rm);
      al[r] = __expf(mrow[r] - mn);
      mrow[r] = mn;
      float ps = 0.f;
#pragma unroll
      for (int ct = 0; ct < 4; ++ct) {
        const float p = __expf(sc[ct][r] - mn);
        sc[ct][r] = p;
        ps += p;
      }
      ps += __shfl_xor(ps, 1);
      ps += __shfl_xor(ps, 2);
      ps += __shfl_xor(ps, 4);
      ps += __shfl_xor(ps, 8);
      lrow[r] = lrow[r] * al[r] + ps;
    }
#pragma unroll
    for (int nt = 0; nt < 8; ++nt)
#pragma unroll
      for (int r = 0; r < 4; ++r) o[nt][r] *= al[r];

#pragma unroll
    for (int ct = 0; ct < 4; ++ct)
#pragma unroll
      for (int r = 0; r < 4; ++r)
        Ps[w][(quad * 4 + r) * 72 + ct * 16 + l15] = f2b(sc[ct][r]);

#pragma unroll
    for (int kt2 = 0; kt2 < 2; ++kt2) {
      V16 pa;
      pa.u = *(const uint4*)&Ps[w][l15 * 72 + kt2 * 32 + quad * 8];
#pragma unroll
      for (int nt = 0; nt < 8; ++nt) {
        V16 vb;
        const int dd = nt * 16 + l15;
        const int gs = (kt2 * 4 + quad) ^ nt;
        vb.u = *(const uint4*)&VTs[dd * 72 + gs * 8];
        o[nt] = mfma16(pa.b, vb.b, o[nt]);
      }
    }
  }

  float invl[4];
#pragma unroll
  for (int r = 0; r < 4; ++r) invl[r] = 1.f / lrow[r];
#pragma unroll
  for (int nt = 0; nt < 8; ++nt) {
#pragma unroll
    for (int r = 0; r < 4; ++r) {
      const int gi = i0 + w * 16 + quad * 4 + r;
      ctx[(size_t)gi * Cw + h * 128 + nt * 16 + l15] = f2b(o[nt][r] * invl[r]);
    }
  }
}

// ---------------- driver ----------------
extern "C" void kernel_launch(void* const* d_in, const int* in_sizes, int n_in,
                              void* d_out, int out_size, void* d_ws, size_t ws_size,
                              hipStream_t stream) {
  (void)in_sizes; (void)n_in; (void)out_size; (void)ws_size;
  const float* hid  = (const float*)d_in[0];
  const float* cosb = (const float*)d_in[1];
  const float* sinb = (const float*)d_in[2];
  // d_in[3] attention_mask: exactly causal -> applied analytically
  const float* ln1w = (const float*)d_in[4];
  const float* wq   = (const float*)d_in[5];
  const float* wk   = (const float*)d_in[6];
  const float* wv   = (const float*)d_in[7];
  const float* wo   = (const float*)d_in[8];
  const float* ln2w = (const float*)d_in[9];
  const float* wg   = (const float*)d_in[10];
  const float* wu   = (const float*)d_in[11];
  const float* wd   = (const float*)d_in[12];
  float* outp = (float*)d_out;

  const size_t SC = (size_t)2048 * 2048;       // 4.19M
  const size_t FC = (size_t)8192 * 2048;       // 16.78M
  unsigned short* p = (unsigned short*)d_ws;
  unsigned short* wqb = p;  p += SC;
  unsigned short* wkb = p;  p += SC;
  unsigned short* wvb = p;  p += SC;
  unsigned short* wob = p;  p += SC;
  unsigned short* wgb = p;  p += FC;
  unsigned short* wub = p;  p += FC;
  unsigned short* wdb = p;  p += FC;
  unsigned short* xn  = p;  p += SC;           // reused as yn
  unsigned short* qb  = p;  p += SC;
  unsigned short* kb  = p;  p += SC;
  unsigned short* vb  = p;  p += SC;
  unsigned short* ctxb = p; p += SC;
  float* hf = (float*)p;   p += 2 * SC;        // f32 h = hidden + attn_out
  float* k2cb = (float*)p;                     // [H][S] = k^2 * c
  unsigned short* yn = xn;                     // xn dead after QKV
  // region reuse after their producers/consumers retire:
  unsigned short* gate = wqb;                  // wq..wo (4*SC) dead after QKV-proj:
                                               //   gate half of gate+up, then fused act
  unsigned short* upb  = qb;                   // qb..ctxb (4*SC) dead after wo-proj:
                                               //   up half of gate+up
  float* pd = (float*)wgb;                     // wg+wu (2*FC shorts = 4*SC floats) dead
                                               //   after gate+up -> 4 down split-K partials

  // 0. all weights f32 -> bf16 (one launch; dst regions contiguous)
  cvt_all<<<65536, 256, 0, stream>>>(wq, wk, wv, wo, wg, wu, wd, wqb);

  // 1. input RMSNorm
  rms_k<<<2048, 256, 0, stream>>>(hid, ln1w, xn);
  // 2. fused QKV projection: single 256^2 8-phase GEMM over contiguous [wq;wk;wv] (N=6144)
  gemm256<1><<<dim3(24, 8, 1), 512, 0, stream>>>(xn, wqb, qb, kb, vb, nullptr,
                                                 6144, 2048, 32);
  // 3. RoPE in-place on q,k + k^2*c precompute
  rope_qk<<<8192, 256, 0, stream>>>(qb, kb, cosb, sinb, k2cb);
  // 4. W2 attention -> ctx
  flash_w2<<<dim3(32, 16), 256, 0, stream>>>(qb, kb, vb, k2cb, ctxb);
  // 5. output projection + residual -> h (f32)  (64 tiles only -> keep 128-wide kernel)
  gemm_nt<1, 2><<<dim3(16, 32, 1), 256, 0, stream>>>(ctxb, wob, wob, wob,
                                                     nullptr, nullptr, nullptr,
                                                     hid, hf, 2048, 2048, 2048);
  // 6. post-attn RMSNorm
  rms_k<<<2048, 256, 0, stream>>>(hf, ln2w, yn);
  // 7. gate+up: single 256^2 8-phase GEMM over contiguous [wg;wu] (N=16384)
  gemm256<0><<<dim3(64, 8, 1), 512, 0, stream>>>(yn, wgb, gate, upb, nullptr, nullptr,
                                                 16384, 2048, 32);
  // 8. silu(g)*u in-place over gate region
  silu_k<<<8192, 256, 0, stream>>>(gate, upb);
  // 9. down GEMM, split-K=4 -> f32 partials over dead wg/wu region
  gemm256<2><<<dim3(8, 8, 4), 512, 0, stream>>>(gate, wdb, nullptr, nullptr, nullptr,
                                                pd, 2048, 8192, 32);
  // 10. combine: out = hf + p0+p1+p2+p3
  comb4<<<4096, 256, 0, stream>>>(pd, hf, outp);
}

// Round 2
// 763.843 us; speedup vs baseline: 1.0808x; 1.0808x over previous
//
#include <hip/hip_runtime.h>
#include <cstdint>
#include <cstddef>

typedef __bf16 bf16x8 __attribute__((ext_vector_type(8)));
typedef float f32x4 __attribute__((ext_vector_type(4)));

union V16 { uint4 u; bf16x8 b; unsigned short s[8]; };

__device__ __forceinline__ float b2f(unsigned short u) {
  unsigned int x = ((unsigned int)u) << 16;
  float f;
  __builtin_memcpy(&f, &x, 4);
  return f;
}
__device__ __forceinline__ unsigned short f2b(float f) {
  unsigned int u;
  __builtin_memcpy(&u, &f, 4);
  u = u + 0x7FFFu + ((u >> 16) & 1u);
  return (unsigned short)(u >> 16);
}

__device__ __forceinline__ f32x4 mfma16(bf16x8 a, bf16x8 b, f32x4 c) {
  return __builtin_amdgcn_mfma_f32_16x16x32_bf16(a, b, c, 0, 0, 0);
}

// async global->LDS, 16B per lane; LDS dest is wave-uniform base (+lane*16 implicit)
__device__ __forceinline__ void gld_lds16(const unsigned short* g, unsigned short* l) {
  __builtin_amdgcn_global_load_lds((__attribute__((address_space(1))) void*)g,
                                   (__attribute__((address_space(3))) void*)l,
                                   16, 0, 0);
}

// ---------------- merged f32 -> bf16 convert (all 7 weights, contiguous dst) ----------------
__global__ __launch_bounds__(256) void cvt_all(const float* __restrict__ wq,
                                               const float* __restrict__ wk,
                                               const float* __restrict__ wv,
                                               const float* __restrict__ wo,
                                               const float* __restrict__ wg,
                                               const float* __restrict__ wu,
                                               const float* __restrict__ wd,
                                               unsigned short* __restrict__ dst) {
  const int b = blockIdx.x;
  const float* src;
  if (b < 16384) {
    const int w = b >> 12;
    src = (w == 0 ? wq : w == 1 ? wk : w == 2 ? wv : wo) + (size_t)(b & 4095) * 1024;
  } else if (b < 32768) {
    src = wg + (size_t)(b - 16384) * 1024;
  } else if (b < 49152) {
    src = wu + (size_t)(b - 32768) * 1024;
  } else {
    src = wd + (size_t)(b - 49152) * 1024;
  }
  const int o = threadIdx.x * 4;
  const float4 v = *(const float4*)(src + o);
  ushort4 r;
  r.x = f2b(v.x); r.y = f2b(v.y); r.z = f2b(v.z); r.w = f2b(v.w);
  *(ushort4*)(dst + (size_t)b * 1024 + o) = r;
}

// ---------------- RMSNorm (f32 in -> bf16 out) ----------------
__global__ __launch_bounds__(256) void rms_k(const float* __restrict__ xin,
                                             const float* __restrict__ wgt,
                                             unsigned short* __restrict__ out) {
  const int s = blockIdx.x;
  const int t = threadIdx.x;
  float vals[8];
  float ss = 0.f;
#pragma unroll
  for (int i = 0; i < 8; ++i) {
    const int c = t + i * 256;
    const float f = xin[(size_t)s * 2048 + c];
    vals[i] = f;
    ss += f * f;
  }
#pragma unroll
  for (int off = 32; off > 0; off >>= 1) ss += __shfl_xor(ss, off);
  __shared__ float red[4];
  if ((t & 63) == 0) red[t >> 6] = ss;
  __syncthreads();
  ss = red[0] + red[1] + red[2] + red[3];
  const float sc = rsqrtf(ss * (1.f / 2048.f) + 1e-6f);
#pragma unroll
  for (int i = 0; i < 8; ++i) {
    const int c = t + i * 256;
    out[(size_t)s * 2048 + c] = f2b(vals[i] * sc * wgt[c]);
  }
}

// ---------------- RoPE (in-place bf16 q,k) + k^2*c precompute ----------------
__global__ __launch_bounds__(256) void rope_qk(unsigned short* qb, unsigned short* kb,
                                               const float* __restrict__ cosb,
                                               const float* __restrict__ sinb,
                                               float* __restrict__ k2c) {
  const int idx = blockIdx.x * 256 + threadIdx.x;  // 0 .. S*H*64
  const int d = idx & 63;
  const int h = (idx >> 6) & 15;
  const int s = idx >> 10;
  const size_t base = (size_t)s * 2048 + h * 128;
  const int cb = s * 128;
  const float c1 = cosb[cb + d],      s1 = sinb[cb + d];
  const float c2 = cosb[cb + d + 64], s2 = sinb[cb + d + 64];
  {
    const float x1 = b2f(qb[base + d]), x2 = b2f(qb[base + d + 64]);
    qb[base + d]      = f2b(x1 * c1 - x2 * s1);
    qb[base + d + 64] = f2b(x2 * c2 + x1 * s2);
  }
  {
    const float x1 = b2f(kb[base + d]), x2 = b2f(kb[base + d + 64]);
    const float k1 = x1 * c1 - x2 * s1;
    const float k2 = x2 * c2 + x1 * s2;
    kb[base + d]      = f2b(k1);
    kb[base + d + 64] = f2b(k2);
    float ss = k1 * k1 + k2 * k2;
#pragma unroll
    for (int off = 32; off > 0; off >>= 1) ss += __shfl_xor(ss, off);
    if (d == 0) k2c[h * 2048 + s] = ss * 0.04419417382415922f;
  }
}

// ---------------- NT GEMM (128-wide, m97 structure) -- kept for wo-proj only ----------------
// EPI 1: Cf[idx] = auxf[idx] + acc (f32 store)
template <int EPI, int RT>
__global__ __launch_bounds__(256, 2) void gemm_nt(
    const unsigned short* __restrict__ A,
    const unsigned short* __restrict__ B0,
    const unsigned short* __restrict__ B1,
    const unsigned short* __restrict__ B2,
    unsigned short* C0, unsigned short* C1, unsigned short* C2,
    const float* auxf, float* Cf,
    int N, int K, int kstride) {
  constexpr int TM = RT * 32;
  constexpr int APASS = TM / 64;
  const unsigned short* B;
  unsigned short* C;
  size_t koff = 0;
  if constexpr (EPI == 0) {
    B = (blockIdx.z == 0) ? B0 : (blockIdx.z == 1 ? B1 : B2);
    C = (blockIdx.z == 0) ? C0 : (blockIdx.z == 1 ? C1 : C2);
  } else {
    B = B0;
    C = C0;
    if constexpr (EPI == 3) koff = (size_t)blockIdx.z * K;
  }

  const int m0 = blockIdx.y * TM;
  const int n0 = blockIdx.x * 128;
  const int t = threadIdx.x;
  const int lane = t & 63;
  const int w = t >> 6;
  const int quad = lane >> 4;
  const int l15 = lane & 15;
  const int wr = w >> 1;
  const int wc = w & 1;

  __shared__ __align__(16) unsigned short As[TM * 32];
  __shared__ __align__(16) unsigned short Bs[128 * 32];

  const f32x4 vzero = {0.f, 0.f, 0.f, 0.f};
  f32x4 acc[RT][4];
#pragma unroll
  for (int i = 0; i < RT; ++i)
#pragma unroll
    for (int j = 0; j < 4; ++j) acc[i][j] = vzero;

  const int srow = w * 16 + (lane >> 2);
  const int scol = (lane & 3) * 8;
  const unsigned short* Ag = A + (size_t)(m0 + srow) * kstride + scol + koff;
  const unsigned short* Bg = B + (size_t)(n0 + srow) * kstride + scol + koff;

  for (int k0 = 0; k0 < K; k0 += 32) {
#pragma unroll
    for (int p = 0; p < APASS; ++p)
      gld_lds16(Ag + (size_t)p * 64 * kstride + k0, As + p * 2048 + w * 512);
#pragma unroll
    for (int p = 0; p < 2; ++p)
      gld_lds16(Bg + (size_t)p * 64 * kstride + k0, Bs + p * 2048 + w * 512);
    __syncthreads();

    bf16x8 af[RT], bfr[4];
#pragma unroll
    for (int rt = 0; rt < RT; ++rt)
      af[rt] = *(const bf16x8*)&As[(wr * (RT * 16) + rt * 16 + l15) * 32 + quad * 8];
#pragma unroll
    for (int ct = 0; ct < 4; ++ct)
      bfr[ct] = *(const bf16x8*)&Bs[(wc * 64 + ct * 16 + l15) * 32 + quad * 8];
#pragma unroll
    for (int rt = 0; rt < RT; ++rt)
#pragma unroll
      for (int ct = 0; ct < 4; ++ct)
        acc[rt][ct] = mfma16(af[rt], bfr[ct], acc[rt][ct]);
    __syncthreads();
  }

  float* Cfz = Cf;
  if constexpr (EPI == 3)
    Cfz = Cf + (size_t)blockIdx.z * (size_t)gridDim.y * TM * N;

#pragma unroll
  for (int rt = 0; rt < RT; ++rt) {
#pragma unroll
    for (int ct = 0; ct < 4; ++ct) {
#pragma unroll
      for (int r = 0; r < 4; ++r) {
        const int m = m0 + wr * (RT * 16) + rt * 16 + quad * 4 + r;
        const int n = n0 + wc * 64 + ct * 16 + l15;
        const size_t idx = (size_t)m * N + n;
        const float a = acc[rt][ct][r];
        if constexpr (EPI == 0) {
          C[idx] = f2b(a);
        } else if constexpr (EPI == 1) {
          Cf[idx] = auxf[idx] + a;
        } else {
          Cfz[idx] = a;
        }
      }
    }
  }
}

// ================= 256x256 8-phase NT GEMM, fine-interleaved (T2+T3+T4+T5) ========
// C[M,N] = A[M,K] @ B[N,K]^T. 512 threads = 8 waves (2M x 4N), per-wave 128x64 output.
// BK=64, split into two 32-wide K-sub chunks. LDS 128 KiB: As/Bs[2 buf][2 ks][256][32].
// Per-tile 4 phases: (ks0,MQ0)(ks0,MQ1)(ks1,MQ0)(ks1,MQ1); per phase: 8/4/8/4 ds_reads,
// ONE staged chunk (2 gld_lds/thread), 16 MFMA. Chunk ring (tile s):
//   ph1: A-ks1(s+1)  ph2: B-ks1(s+1)+vmcnt(8)  ph3: A-ks0(s+2)  ph4: B-ks0(s+2)+vmcnt(8)
// ks0 region of the read buffer is dead after ph2, so ph3/ph4 staging into it is safe
// (barrier-ordered). Each chunk rides ~4 phases before its counted-vmcnt gate.
// Swizzle: 16B-unit u at row r holds global unit u ^ ((r>>1)&3); inverse-swizzled global
// source + linear gld_lds dest + swizzled ds_read offset (rule #21 involution).
#define BARRIER() asm volatile("s_barrier" ::: "memory")
#define WAITVM(N) asm volatile("s_waitcnt vmcnt(" #N ")" ::: "memory")
#define WAITLG()                                           \
  do {                                                     \
    asm volatile("s_waitcnt lgkmcnt(0)" ::: "memory");     \
    __builtin_amdgcn_sched_barrier(0);                     \
  } while (0)

#define LDA(BUF, KS, MQ)                                                       \
  _Pragma("unroll") for (int j = 0; j < 4; ++j)                                \
      afr[j] = *(const bf16x8*)(aB + (BUF) * 16384 + (KS) * 8192 +             \
                                ((MQ) * 64 + j * 16) * 32);

#define LDB(BUF, KS)                                                           \
  _Pragma("unroll") for (int nf = 0; nf < 4; ++nf)                             \
      bfr[nf] = *(const bf16x8*)(bB + (BUF) * 16384 + (KS) * 8192 +            \
                                 (nf * 16) * 32);

#define MF(MQ)                                                                 \
  do {                                                                         \
    __builtin_amdgcn_s_setprio(1);                                             \
    _Pragma("unroll") for (int j = 0; j < 4; ++j)                              \
    _Pragma("unroll") for (int nf = 0; nf < 4; ++nf)                           \
        acc[(MQ) * 4 + j][nf] = mfma16(afr[j], bfr[nf], acc[(MQ) * 4 + j][nf]);\
    __builtin_amdgcn_s_setprio(0);                                             \
  } while (0)

// stage one 256x32 chunk (A or B): 2 gld_lds/thread, then advance k by 32
#define STA(BUF, KS)                                                           \
  do {                                                                         \
    unsigned short* d_ = AsB + (BUF) * 16384 + (KS) * 8192 + w * 512;          \
    gld_lds16(pA, d_);                                                         \
    gld_lds16(pA + (size_t)128 * kstr, d_ + 4096);                             \
    pA += 32;                                                                  \
  } while (0)

#define STB(BUF, KS)                                                           \
  do {                                                                         \
    unsigned short* d_ = BsB + (BUF) * 16384 + (KS) * 8192 + w * 512;          \
    gld_lds16(pB, d_);                                                         \
    gld_lds16(pB + (size_t)128 * kstr, d_ + 4096);                             \
    pB += 32;                                                                  \
  } while (0)

// steady tile on buffer P: stages next tiles' chunks, two counted waits
#define TILE_STEADY(P)                                                         \
  do {                                                                         \
    LDA(P, 0, 0); LDB(P, 0); STA((P) ^ 1, 1);                                  \
    BARRIER(); WAITLG(); MF(0); BARRIER();                                     \
    LDA(P, 0, 1);            STB((P) ^ 1, 1);                                  \
    BARRIER(); WAITLG(); MF(1); WAITVM(8); BARRIER();                          \
    LDA(P, 1, 0); LDB(P, 1); STA(P, 0);                                        \
    BARRIER(); WAITLG(); MF(0); BARRIER();                                     \
    LDA(P, 1, 1);            STB(P, 0);                                        \
    BARRIER(); WAITLG(); MF(1); WAITVM(8); BARRIER();                          \
  } while (0)

// EPI 0: bf16 out split at n=8192 -> C0/C1 (gate+up).   EPI 1: bf16 3-way split at
// n=2048 -> C0/C1/C2 (QKV).   EPI 2: f32 split-K partial Cf + z*M*N, A/B offset z*Ktiles*64.
template <int EPI>
__global__ __launch_bounds__(512, 2) void gemm256(
    const unsigned short* __restrict__ A,
    const unsigned short* __restrict__ B,
    unsigned short* __restrict__ C0,
    unsigned short* __restrict__ C1,
    unsigned short* __restrict__ C2,
    float* __restrict__ Cf,
    int N, int kstr, int Ktiles) {
  // XCD-chunked block swizzle (bijective; all grids here are %8==0)
  const int gx = gridDim.x, gy = gridDim.y;
  const int nwg = gx * gy * gridDim.z;
  const int orig = blockIdx.x + gx * (blockIdx.y + gy * blockIdx.z);
  const int s = ((nwg & 7) == 0) ? ((orig & 7) * (nwg >> 3) + (orig >> 3)) : orig;
  const int bx = s % gx;
  const int sq = s / gx;
  const int by = sq % gy;
  const int bz = sq / gy;

  const int m0 = by * 256, n0 = bx * 256;
  const size_t koff = (size_t)bz * ((size_t)Ktiles * 64);

  const int t = threadIdx.x;
  const int lane = t & 63;
  const int w = t >> 6;
  const int quad = lane >> 4;
  const int l15 = lane & 15;
  const int wr = w >> 2;
  const int wc = w & 3;

  __shared__ __align__(16) unsigned short As[2][2][8192];
  __shared__ __align__(16) unsigned short Bs[2][2][8192];
  unsigned short* AsB = &As[0][0][0];
  unsigned short* BsB = &Bs[0][0][0];

  const f32x4 vzero = {0.f, 0.f, 0.f, 0.f};
  f32x4 acc[8][4];
#pragma unroll
  for (int i = 0; i < 8; ++i)
#pragma unroll
    for (int j = 0; j < 4; ++j) acc[i][j] = vzero;

  bf16x8 afr[4], bfr[4];

  // ds_read swizzled unit offset (shorts): phys unit = quad ^ ((row>>1)&3), row ≡ l15 mod 16
  const int ko = (quad ^ ((l15 >> 1) & 3)) * 8;
  const unsigned short* aB = AsB + wr * 4096 + l15 * 32 + ko;   // wr*128 rows
  const unsigned short* bB = BsB + wc * 2048 + l15 * 32 + ko;   // wc*64 rows

  // staging source: thread covers row w*16+(lane>>2) (+128 for 2nd issue), unit lane&3;
  // source unit pre-swizzled so linear LDS dest lands swizzled
  const int usrc = (lane & 3) ^ ((lane >> 3) & 3);
  const unsigned short* pA =
      A + (size_t)(m0 + w * 16 + (lane >> 2)) * kstr + koff + usrc * 8;
  const unsigned short* pB =
      B + (size_t)(n0 + w * 16 + (lane >> 2)) * kstr + koff + usrc * 8;

  // prologue: chunks A0(0) B0(0) A1(0) B1(0) A0(1) B0(1); wait oldest 2 chunks
  STA(0, 0); STB(0, 0);
  STA(0, 1); STB(0, 1);
  STA(1, 0); STB(1, 0);
  WAITVM(8);
  BARRIER();

  const int pairs = (Ktiles - 2) >> 1;   // tiles 0..Ktiles-3 steady
  for (int it = 0; it < pairs; ++it) {
    TILE_STEADY(0);
    TILE_STEADY(1);
  }
  // tail tile Ktiles-2 (buf0): stage only ks1 of last tile; drain 8 -> 4
  LDA(0, 0, 0); LDB(0, 0); STA(1, 1);
  BARRIER(); WAITLG(); MF(0); BARRIER();
  LDA(0, 0, 1);            STB(1, 1);
  BARRIER(); WAITLG(); MF(1); WAITVM(8); BARRIER();
  LDA(0, 1, 0); LDB(0, 1);
  BARRIER(); WAITLG(); MF(0); BARRIER();
  LDA(0, 1, 1);
  BARRIER(); WAITLG(); MF(1); WAITVM(4); BARRIER();
  // tail tile Ktiles-1 (buf1): drain 0
  LDA(1, 0, 0); LDB(1, 0);
  BARRIER(); WAITLG(); MF(0); BARRIER();
  LDA(1, 0, 1);
  BARRIER(); WAITLG(); MF(1); WAITVM(0); BARRIER();
  LDA(1, 1, 0); LDB(1, 1);
  BARRIER(); WAITLG(); MF(0); BARRIER();
  LDA(1, 1, 1);
  BARRIER(); WAITLG(); MF(1);

  // ----- epilogue -----
  if constexpr (EPI == 2) {
    const size_t MN = (size_t)gy * 256 * N;
    float* Cp = Cf + (size_t)bz * MN;
#pragma unroll
    for (int mf = 0; mf < 8; ++mf) {
      const int m = m0 + wr * 128 + mf * 16 + quad * 4;
#pragma unroll
      for (int nf = 0; nf < 4; ++nf) {
        const int n = n0 + wc * 64 + nf * 16 + l15;
#pragma unroll
        for (int r = 0; r < 4; ++r) Cp[(size_t)(m + r) * N + n] = acc[mf][nf][r];
      }
    }
  } else {
    unsigned short* Cp;
    int nb;
    constexpr int ldc = (EPI == 0) ? 8192 : 2048;
    if constexpr (EPI == 0) {
      Cp = (n0 < 8192) ? C0 : C1;   // block-uniform (8192 % 256 == 0)
      nb = n0 & 8191;
    } else {
      const int wsel = n0 >> 11;    // block-uniform (2048 % 256 == 0)
      Cp = wsel == 0 ? C0 : (wsel == 1 ? C1 : C2);
      nb = n0 & 2047;
    }
#pragma unroll
    for (int mf = 0; mf < 8; ++mf) {
      const int m = m0 + wr * 128 + mf * 16 + quad * 4;
#pragma unroll
      for (int nf = 0; nf < 4; ++nf) {
        const int n = nb + wc * 64 + nf * 16 + l15;
#pragma unroll
        for (int r = 0; r < 4; ++r)
          Cp[(size_t)(m + r) * ldc + n] = f2b(acc[mf][nf][r]);
      }
    }
  }
}

// ---------------- silu(g)*u elementwise, in-place over g ----------------
__global__ __launch_bounds__(256) void silu_k(unsigned short* __restrict__ g,
                                              const unsigned short* __restrict__ u) {
  const size_t i = ((size_t)blockIdx.x * 256 + threadIdx.x) * 8;
  V16 gv, uv, ov;
  gv.u = *(const uint4*)(g + i);
  uv.u = *(const uint4*)(u + i);
#pragma unroll
  for (int e = 0; e < 8; ++e) {
    const float gf = b2f(gv.s[e]);
    const float uf = b2f(uv.s[e]);
    ov.s[e] = f2b(gf / (1.f + __expf(-gf)) * uf);
  }
  *(uint4*)(g + i) = ov.u;
}

// ---------------- split-K=4 combine: out = hf + p0+p1+p2+p3 ----------------
__global__ __launch_bounds__(256) void comb4(const float* __restrict__ p,
                                             const float* __restrict__ hf,
                                             float* __restrict__ out) {
  const size_t i = ((size_t)blockIdx.x * 256 + threadIdx.x) * 4;
  const size_t MN = (size_t)2048 * 2048;
  float4 a = *(const float4*)(p + i);
  const float4 b = *(const float4*)(p + MN + i);
  const float4 c = *(const float4*)(p + 2 * MN + i);
  const float4 d = *(const float4*)(p + 3 * MN + i);
  const float4 h = *(const float4*)(hf + i);
  a.x += b.x + c.x + d.x + h.x;
  a.y += b.y + c.y + d.y + h.y;
  a.z += b.z + c.z + d.z + h.z;
  a.w += b.w + c.w + d.w + h.w;
  *(float4*)(out + i) = a;
}

// ---------------- Flash W2 (Gaussian-kernel) attention ----------------
__global__ __launch_bounds__(256, 3) void flash_w2(
    const unsigned short* __restrict__ q,
    const unsigned short* __restrict__ kk,
    const unsigned short* __restrict__ v,
    const float* __restrict__ k2c,
    unsigned short* __restrict__ ctx) {
  constexpr int Cw = 2048;
  constexpr float TWOC = 0.08838834764831843f;  // 1/sqrt(128)
  const int h = blockIdx.y;
  const int i = (h >= 8) ? (31 - blockIdx.x) : blockIdx.x;
  const int i0 = i * 64;
  const int t = threadIdx.x;
  const int lane = t & 63;
  const int w = t >> 6;
  const int quad = lane >> 4;
  const int l15 = lane & 15;

  __shared__ __align__(16) unsigned short Ks[64 * 136];   // [j][d], pitch 136
  __shared__ __align__(16) unsigned short VTs[128 * 72];  // [d][j^], XOR-swizzled
  __shared__ __align__(16) unsigned short Ps[4][16 * 72]; // per-wave P

  bf16x8 aq[4];
  {
    const unsigned short* qp = q + (size_t)(i0 + w * 16 + l15) * Cw + h * 128;
#pragma unroll
    for (int kt = 0; kt < 4; ++kt) {
      V16 u;
      u.u = *(const uint4*)(qp + kt * 32 + quad * 8);
      aq[kt] = u.b;
    }
  }

  const f32x4 vzero = {0.f, 0.f, 0.f, 0.f};
  f32x4 o[8];
#pragma unroll
  for (int nt = 0; nt < 8; ++nt) o[nt] = vzero;
  float mrow[4] = {-1e30f, -1e30f, -1e30f, -1e30f};
  float lrow[4] = {0.f, 0.f, 0.f, 0.f};

  const int njt = i + 1;
  const int jr = t >> 2;
  const int c0 = (t & 3) * 32;
  const int jlo = jr & 7;
  const int jhi = jr >> 3;
  for (int jt = 0; jt < njt; ++jt) {
    const int j0 = jt * 64;
    __syncthreads();
    {
      const unsigned short* kp = kk + (size_t)(j0 + jr) * Cw + h * 128 + c0;
      const unsigned short* vp = v + (size_t)(j0 + jr) * Cw + h * 128 + c0;
#pragma unroll
      for (int ii = 0; ii < 4; ++ii) {
        *(uint4*)&Ks[jr * 136 + c0 + ii * 8] = *(const uint4*)(kp + ii * 8);
        V16 vu;
        vu.u = *(const uint4*)(vp + ii * 8);
#pragma unroll
        for (int e = 0; e < 8; ++e) {
          const int dd = c0 + ii * 8 + e;
          const int gs = (jhi ^ (dd >> 4)) & 7;
          VTs[dd * 72 + (jlo | (gs << 3))] = vu.s[e];
        }
      }
    }
    __syncthreads();

    float k2v[4];
#pragma unroll
    for (int ct = 0; ct < 4; ++ct) k2v[ct] = k2c[h * 2048 + j0 + ct * 16 + l15];

    f32x4 sc[4];
#pragma unroll
    for (int ct = 0; ct < 4; ++ct) {
      f32x4 a = vzero;
#pragma unroll
      for (int kt = 0; kt < 4; ++kt) {
        V16 u;
        u.u = *(const uint4*)&Ks[(ct * 16 + l15) * 136 + kt * 32 + quad * 8];
        a = mfma16(aq[kt], u.b, a);
      }
      sc[ct] = a;
    }

    const bool diag = (jt == njt - 1);
#pragma unroll
    for (int ct = 0; ct < 4; ++ct) {
#pragma unroll
      for (int r = 0; r < 4; ++r) {
        float s = fmaf(TWOC, sc[ct][r], -k2v[ct]);
        if (diag) {
          const int gi = w * 16 + quad * 4 + r;
          const int gj = ct * 16 + l15;
          s = (gj <= gi) ? s : -1e30f;
        }
        sc[ct][r] = s;
      }
    }

    float al[4];
#pragma unroll
    for (int r = 0; r < 4; ++r) {
      float rm = fmaxf(fmaxf(sc[0][r], sc[1][r]), fmaxf(sc[2][r], sc[3][r]));
      rm = fmaxf(rm, __shfl_xor(rm, 1));
      rm = fmaxf(rm, __shfl_xor(rm, 2));
      rm = fmaxf(rm, __shfl_xor(rm, 4));
      rm = fmaxf(rm, __shfl_xor(rm, 8));
      const float mn = fmaxf(mrow[r], rm);
      al[r] = __expf(mrow[r] - mn);
      mrow[r] = mn;
      float ps = 0.f;
#pragma unroll
      for (int ct = 0; ct < 4; ++ct) {
        const float p = __expf(sc[ct][r] - mn);
        sc[ct][r] = p;
        ps += p;
      }
      ps += __shfl_xor(ps, 1);
      ps += __shfl_xor(ps, 2);
      ps += __shfl_xor(ps, 4);
      ps += __shfl_xor(ps, 8);
      lrow[r] = lrow[r] * al[r] + ps;
    }
#pragma unroll
    for (int nt = 0; nt < 8; ++nt)
#pragma unroll
      for (int r = 0; r < 4; ++r) o[nt][r] *= al[r];

#pragma unroll
    for (int ct = 0; ct < 4; ++ct)
#pragma unroll
      for (int r = 0; r < 4; ++r)
        Ps[w][(quad * 4 + r) * 72 + ct * 16 + l15] = f2b(sc[ct][r]);

#pragma unroll
    for (int kt2 = 0; kt2 < 2; ++kt2) {
      V16 pa;
      pa.u = *(const uint4*)&Ps[w][l15 * 72 + kt2 * 32 + quad * 8];
#pragma unroll
      for (int nt = 0; nt < 8; ++nt) {
        V16 vb;
        const int dd = nt * 16 + l15;
        const int gs = (kt2 * 4 + quad) ^ nt;
        vb.u = *(const uint4*)&VTs[dd * 72 + gs * 8];
        o[nt] = mfma16(pa.b, vb.b, o[nt]);
      }
    }
  }

  float invl[4];
#pragma unroll
  for (int r = 0; r < 4; ++r) invl[r] = 1.f / lrow[r];
#pragma unroll
  for (int nt = 0; nt < 8; ++nt) {
#pragma unroll
    for (int r = 0; r < 4; ++r) {
      const int gi = i0 + w * 16 + quad * 4 + r;
      ctx[(size_t)gi * Cw + h * 128 + nt * 16 + l15] = f2b(o[nt][r] * invl[r]);
    }
  }
}

// ---------------- driver ----------------
extern "C" void kernel_launch(void* const* d_in, const int* in_sizes, int n_in,
                              void* d_out, int out_size, void* d_ws, size_t ws_size,
                              hipStream_t stream) {
  (void)in_sizes; (void)n_in; (void)out_size; (void)ws_size;
  const float* hid  = (const float*)d_in[0];
  const float* cosb = (const float*)d_in[1];
  const float* sinb = (const float*)d_in[2];
  // d_in[3] attention_mask: exactly causal -> applied analytically
  const float* ln1w = (const float*)d_in[4];
  const float* wq   = (const float*)d_in[5];
  const float* wk   = (const float*)d_in[6];
  const float* wv   = (const float*)d_in[7];
  const float* wo   = (const float*)d_in[8];
  const float* ln2w = (const float*)d_in[9];
  const float* wg   = (const float*)d_in[10];
  const float* wu   = (const float*)d_in[11];
  const float* wd   = (const float*)d_in[12];
  float* outp = (float*)d_out;

  const size_t SC = (size_t)2048 * 2048;       // 4.19M
  const size_t FC = (size_t)8192 * 2048;       // 16.78M
  unsigned short* p = (unsigned short*)d_ws;
  unsigned short* wqb = p;  p += SC;
  unsigned short* wkb = p;  p += SC;
  unsigned short* wvb = p;  p += SC;
  unsigned short* wob = p;  p += SC;
  unsigned short* wgb = p;  p += FC;
  unsigned short* wub = p;  p += FC;
  unsigned short* wdb = p;  p += FC;
  unsigned short* xn  = p;  p += SC;           // reused as yn
  unsigned short* qb  = p;  p += SC;
  unsigned short* kb  = p;  p += SC;
  unsigned short* vb  = p;  p += SC;
  unsigned short* ctxb = p; p += SC;
  float* hf = (float*)p;   p += 2 * SC;        // f32 h = hidden + attn_out
  float* k2cb = (float*)p;                     // [H][S] = k^2 * c
  unsigned short* yn = xn;                     // xn dead after QKV
  // region reuse after their producers/consumers retire:
  unsigned short* gate = wqb;                  // wq..wo (4*SC) dead after QKV-proj:
                                               //   gate half of gate+up, then fused act
  unsigned short* upb  = qb;                   // qb..ctxb (4*SC) dead after wo-proj:
                                               //   up half of gate+up
  float* pd = (float*)wgb;                     // wg+wu (2*FC shorts = 4*SC floats) dead
                                               //   after gate+up -> 4 down split-K partials

  // 0. all weights f32 -> bf16 (one launch; dst regions contiguous)
  cvt_all<<<65536, 256, 0, stream>>>(wq, wk, wv, wo, wg, wu, wd, wqb);

  // 1. input RMSNorm
  rms_k<<<2048, 256, 0, stream>>>(hid, ln1w, xn);
  // 2. fused QKV projection: single 256^2 8-phase GEMM over contiguous [wq;wk;wv] (N=6144)
  gemm256<1><<<dim3(24, 8, 1), 512, 0, stream>>>(xn, wqb, qb, kb, vb, nullptr,
                                                 6144, 2048, 32);
  // 3. RoPE in-place on q,k + k^2*c precompute
  rope_qk<<<8192, 256, 0, stream>>>(qb, kb, cosb, sinb, k2cb);
  // 4. W2 attention -> ctx
  flash_w2<<<dim3(32, 16), 256, 0, stream>>>(qb, kb, vb, k2cb, ctxb);
  // 5. output projection + residual -> h (f32)  (64 tiles only -> keep 128-wide kernel)
  gemm_nt<1, 2><<<dim3(16, 32, 1), 256, 0, stream>>>(ctxb, wob, wob, wob,
                                                     nullptr, nullptr, nullptr,
                                                     hid, hf, 2048, 2048, 2048);
  // 6. post-attn RMSNorm
  rms_k<<<2048, 256, 0, stream>>>(hf, ln2w, yn);
  // 7. gate+up: single 256^2 8-phase GEMM over contiguous [wg;wu] (N=16384)
  gemm256<0><<<dim3(64, 8, 1), 512, 0, stream>>>(yn, wgb, gate, upb, nullptr, nullptr,
                                                 16384, 2048, 32);
  // 8. silu(g)*u in-place over gate region
  silu_k<<<8192, 256, 0, stream>>>(gate, upb);
  // 9. down GEMM, split-K=4 -> f32 partials over dead wg/wu region
  gemm256<2><<<dim3(8, 8, 4), 512, 0, stream>>>(gate, wdb, nullptr, nullptr, nullptr,
                                                pd, 2048, 8192, 32);
  // 10. combine: out = hf + p0+p1+p2+p3
  comb4<<<4096, 256, 0, stream>>>(pd, hf, outp);
}

// Round 4
// 761.907 us; speedup vs baseline: 1.0835x; 1.0025x over previous
//
#include <hip/hip_runtime.h>
#include <cstdint>
#include <cstddef>

typedef __bf16 bf16x8 __attribute__((ext_vector_type(8)));
typedef float f32x4 __attribute__((ext_vector_type(4)));

union V16 { uint4 u; bf16x8 b; unsigned short s[8]; };

__device__ __forceinline__ float b2f(unsigned short u) {
  unsigned int x = ((unsigned int)u) << 16;
  float f;
  __builtin_memcpy(&f, &x, 4);
  return f;
}
__device__ __forceinline__ unsigned short f2b(float f) {
  unsigned int u;
  __builtin_memcpy(&u, &f, 4);
  u = u + 0x7FFFu + ((u >> 16) & 1u);
  return (unsigned short)(u >> 16);
}

__device__ __forceinline__ f32x4 mfma16(bf16x8 a, bf16x8 b, f32x4 c) {
  return __builtin_amdgcn_mfma_f32_16x16x32_bf16(a, b, c, 0, 0, 0);
}

// async global->LDS, 16B per lane; LDS dest is wave-uniform base (+lane*16 implicit)
__device__ __forceinline__ void gld_lds16(const unsigned short* g, unsigned short* l) {
  __builtin_amdgcn_global_load_lds((__attribute__((address_space(1))) void*)g,
                                   (__attribute__((address_space(3))) void*)l,
                                   16, 0, 0);
}

// ---------------- merged f32 -> bf16 convert (all 7 weights, contiguous dst) ----------------
__global__ __launch_bounds__(256) void cvt_all(const float* __restrict__ wq,
                                               const float* __restrict__ wk,
                                               const float* __restrict__ wv,
                                               const float* __restrict__ wo,
                                               const float* __restrict__ wg,
                                               const float* __restrict__ wu,
                                               const float* __restrict__ wd,
                                               unsigned short* __restrict__ dst) {
  const int b = blockIdx.x;
  const float* src;
  if (b < 16384) {
    const int w = b >> 12;
    src = (w == 0 ? wq : w == 1 ? wk : w == 2 ? wv : wo) + (size_t)(b & 4095) * 1024;
  } else if (b < 32768) {
    src = wg + (size_t)(b - 16384) * 1024;
  } else if (b < 49152) {
    src = wu + (size_t)(b - 32768) * 1024;
  } else {
    src = wd + (size_t)(b - 49152) * 1024;
  }
  const int o = threadIdx.x * 4;
  const float4 v = *(const float4*)(src + o);
  ushort4 r;
  r.x = f2b(v.x); r.y = f2b(v.y); r.z = f2b(v.z); r.w = f2b(v.w);
  *(ushort4*)(dst + (size_t)b * 1024 + o) = r;
}

// ---------------- RMSNorm (f32 in -> bf16 out) ----------------
__global__ __launch_bounds__(256) void rms_k(const float* __restrict__ xin,
                                             const float* __restrict__ wgt,
                                             unsigned short* __restrict__ out) {
  const int s = blockIdx.x;
  const int t = threadIdx.x;
  float vals[8];
  float ss = 0.f;
#pragma unroll
  for (int i = 0; i < 8; ++i) {
    const int c = t + i * 256;
    const float f = xin[(size_t)s * 2048 + c];
    vals[i] = f;
    ss += f * f;
  }
#pragma unroll
  for (int off = 32; off > 0; off >>= 1) ss += __shfl_xor(ss, off);
  __shared__ float red[4];
  if ((t & 63) == 0) red[t >> 6] = ss;
  __syncthreads();
  ss = red[0] + red[1] + red[2] + red[3];
  const float sc = rsqrtf(ss * (1.f / 2048.f) + 1e-6f);
#pragma unroll
  for (int i = 0; i < 8; ++i) {
    const int c = t + i * 256;
    out[(size_t)s * 2048 + c] = f2b(vals[i] * sc * wgt[c]);
  }
}

// ---------------- RoPE (in-place bf16 q,k) + k^2*c precompute ----------------
__global__ __launch_bounds__(256) void rope_qk(unsigned short* qb, unsigned short* kb,
                                               const float* __restrict__ cosb,
                                               const float* __restrict__ sinb,
                                               float* __restrict__ k2c) {
  const int idx = blockIdx.x * 256 + threadIdx.x;  // 0 .. S*H*64
  const int d = idx & 63;
  const int h = (idx >> 6) & 15;
  const int s = idx >> 10;
  const size_t base = (size_t)s * 2048 + h * 128;
  const int cb = s * 128;
  const float c1 = cosb[cb + d],      s1 = sinb[cb + d];
  const float c2 = cosb[cb + d + 64], s2 = sinb[cb + d + 64];
  {
    const float x1 = b2f(qb[base + d]), x2 = b2f(qb[base + d + 64]);
    qb[base + d]      = f2b(x1 * c1 - x2 * s1);
    qb[base + d + 64] = f2b(x2 * c2 + x1 * s2);
  }
  {
    const float x1 = b2f(kb[base + d]), x2 = b2f(kb[base + d + 64]);
    const float k1 = x1 * c1 - x2 * s1;
    const float k2 = x2 * c2 + x1 * s2;
    kb[base + d]      = f2b(k1);
    kb[base + d + 64] = f2b(k2);
    float ss = k1 * k1 + k2 * k2;
#pragma unroll
    for (int off = 32; off > 0; off >>= 1) ss += __shfl_xor(ss, off);
    if (d == 0) k2c[h * 2048 + s] = ss * 0.04419417382415922f;
  }
}

// ---------------- NT GEMM (128-wide, m97 structure) -- kept for wo-proj only ----------------
// EPI 1: Cf[idx] = auxf[idx] + acc (f32 store)
template <int EPI, int RT>
__global__ __launch_bounds__(256, 2) void gemm_nt(
    const unsigned short* __restrict__ A,
    const unsigned short* __restrict__ B0,
    const unsigned short* __restrict__ B1,
    const unsigned short* __restrict__ B2,
    unsigned short* C0, unsigned short* C1, unsigned short* C2,
    const float* auxf, float* Cf,
    int N, int K, int kstride) {
  constexpr int TM = RT * 32;
  constexpr int APASS = TM / 64;
  const unsigned short* B;
  unsigned short* C;
  size_t koff = 0;
  if constexpr (EPI == 0) {
    B = (blockIdx.z == 0) ? B0 : (blockIdx.z == 1 ? B1 : B2);
    C = (blockIdx.z == 0) ? C0 : (blockIdx.z == 1 ? C1 : C2);
  } else {
    B = B0;
    C = C0;
    if constexpr (EPI == 3) koff = (size_t)blockIdx.z * K;
  }

  const int m0 = blockIdx.y * TM;
  const int n0 = blockIdx.x * 128;
  const int t = threadIdx.x;
  const int lane = t & 63;
  const int w = t >> 6;
  const int quad = lane >> 4;
  const int l15 = lane & 15;
  const int wr = w >> 1;
  const int wc = w & 1;

  __shared__ __align__(16) unsigned short As[TM * 32];
  __shared__ __align__(16) unsigned short Bs[128 * 32];

  const f32x4 vzero = {0.f, 0.f, 0.f, 0.f};
  f32x4 acc[RT][4];
#pragma unroll
  for (int i = 0; i < RT; ++i)
#pragma unroll
    for (int j = 0; j < 4; ++j) acc[i][j] = vzero;

  const int srow = w * 16 + (lane >> 2);
  const int scol = (lane & 3) * 8;
  const unsigned short* Ag = A + (size_t)(m0 + srow) * kstride + scol + koff;
  const unsigned short* Bg = B + (size_t)(n0 + srow) * kstride + scol + koff;

  for (int k0 = 0; k0 < K; k0 += 32) {
#pragma unroll
    for (int p = 0; p < APASS; ++p)
      gld_lds16(Ag + (size_t)p * 64 * kstride + k0, As + p * 2048 + w * 512);
#pragma unroll
    for (int p = 0; p < 2; ++p)
      gld_lds16(Bg + (size_t)p * 64 * kstride + k0, Bs + p * 2048 + w * 512);
    __syncthreads();

    bf16x8 af[RT], bfr[4];
#pragma unroll
    for (int rt = 0; rt < RT; ++rt)
      af[rt] = *(const bf16x8*)&As[(wr * (RT * 16) + rt * 16 + l15) * 32 + quad * 8];
#pragma unroll
    for (int ct = 0; ct < 4; ++ct)
      bfr[ct] = *(const bf16x8*)&Bs[(wc * 64 + ct * 16 + l15) * 32 + quad * 8];
#pragma unroll
    for (int rt = 0; rt < RT; ++rt)
#pragma unroll
      for (int ct = 0; ct < 4; ++ct)
        acc[rt][ct] = mfma16(af[rt], bfr[ct], acc[rt][ct]);
    __syncthreads();
  }

  float* Cfz = Cf;
  if constexpr (EPI == 3)
    Cfz = Cf + (size_t)blockIdx.z * (size_t)gridDim.y * TM * N;

#pragma unroll
  for (int rt = 0; rt < RT; ++rt) {
#pragma unroll
    for (int ct = 0; ct < 4; ++ct) {
#pragma unroll
      for (int r = 0; r < 4; ++r) {
        const int m = m0 + wr * (RT * 16) + rt * 16 + quad * 4 + r;
        const int n = n0 + wc * 64 + ct * 16 + l15;
        const size_t idx = (size_t)m * N + n;
        const float a = acc[rt][ct][r];
        if constexpr (EPI == 0) {
          C[idx] = f2b(a);
        } else if constexpr (EPI == 1) {
          Cf[idx] = auxf[idx] + a;
        } else {
          Cfz[idx] = a;
        }
      }
    }
  }
}

// ================= 256x256 NT GEMM, hoisted-read pipeline (T2+T4+T5, 2 barriers/tile) ======
// C[M,N] = A[M,K] @ B[N,K]^T. 512 threads = 8 waves (2M x 4N), per-wave 128x64 output.
// BK=64 as two 32-wide K-subs. LDS 128 KiB: As/Bs[2 buf][2 ks][256][32].
// 4 self-contained phases/tile: (ks0,mq0)(ks0,mq1)(ks1,mq0)(ks1,mq1), each 8 ds_reads
// (4 A + 4 B, B re-read per phase -> no cross-phase register carry) + 16 MFMA.
// KEY: phase N+1's ds_reads issue immediately after phase N's MFMA cluster, double-
// buffered into afrA/bfrA vs afrB/bfrB -> LDS service hides under MFMA execution.
// Region safety (only 2 barriers/tile):
//   - ks1 of the read buffer is never written mid-tile (stages target other buf / ks0);
//   - ks0 overwrites (ST3/ST4, data for tile t+2) issue only after BARRIER_a, which
//     post-dates the lgkm-drain of every ks0 read (ph1/ph2) in all waves;
//   - boundary: WAITVM(4) (forces all of tile t+1's 4 chunks; leaves 2 newest) + BARRIER.
// Stage ring per tile t (buf P): ST1=A-ks1(t+1), ST2=B-ks1(t+1) [into P^1, fully dead],
// ST3=A-ks0(t+2), ST4=B-ks0(t+2) [into P, dead region]. Tail: tile Kt-2 gates vmcnt(0).
// Swizzle (rule #21 involution): LDS 16B-unit u at row r holds global unit u ^ ((r>>1)&3);
// inverse-swizzled global source + linear gld_lds dest + swizzled ds_read offset.
#define BARRIER() asm volatile("s_barrier" ::: "memory")
#define WAITVM(N) asm volatile("s_waitcnt vmcnt(" #N ")" ::: "memory")
#define WAITLG()                                           \
  do {                                                     \
    asm volatile("s_waitcnt lgkmcnt(0)" ::: "memory");     \
    __builtin_amdgcn_sched_barrier(0);                     \
  } while (0)

// read fragment set SET (A or B regs) for phase (BUF, KS, MQ): 4 A-frags + 4 B-frags
#define RD(SET, BUF, KS, MQ)                                                   \
  do {                                                                         \
    _Pragma("unroll") for (int j = 0; j < 4; ++j)                              \
        afr##SET[j] = *(const bf16x8*)(aB + (BUF) * 16384 + (KS) * 8192 +      \
                                       ((MQ) * 64 + j * 16) * 32);             \
    _Pragma("unroll") for (int nf = 0; nf < 4; ++nf)                           \
        bfr##SET[nf] = *(const bf16x8*)(bB + (BUF) * 16384 + (KS) * 8192 +     \
                                        (nf * 16) * 32);                       \
  } while (0)

#define MFS(SET, MQ)                                                           \
  do {                                                                         \
    __builtin_amdgcn_s_setprio(1);                                             \
    _Pragma("unroll") for (int j = 0; j < 4; ++j)                              \
    _Pragma("unroll") for (int nf = 0; nf < 4; ++nf)                           \
        acc[(MQ) * 4 + j][nf] =                                                \
            mfma16(afr##SET[j], bfr##SET[nf], acc[(MQ) * 4 + j][nf]);          \
    __builtin_amdgcn_s_setprio(0);                                             \
  } while (0)

// stage one 256x32 chunk (A or B): 2 gld_lds/thread, then advance k by 32
#define STA(BUF, KS)                                                           \
  do {                                                                         \
    unsigned short* d_ = AsB + (BUF) * 16384 + (KS) * 8192 + w * 512;          \
    gld_lds16(pA, d_);                                                         \
    gld_lds16(pA + (size_t)128 * kstr, d_ + 4096);                             \
    pA += 32;                                                                  \
  } while (0)

#define STB(BUF, KS)                                                           \
  do {                                                                         \
    unsigned short* d_ = BsB + (BUF) * 16384 + (KS) * 8192 + w * 512;          \
    gld_lds16(pB, d_);                                                         \
    gld_lds16(pB + (size_t)128 * kstr, d_ + 4096);                             \
    pB += 32;                                                                  \
  } while (0)

#define NOSTG do {} while (0)

// one K-tile on buffer P; ST1..ST4 = stage hooks, GATE = counted-vmcnt hook
#define TILE3(P, ST1, ST2, ST3, ST4, GATE)                                     \
  do {                                                                         \
    RD(A, P, 0, 0); ST1;                                                       \
    WAITLG(); MFS(A, 0); RD(B, P, 0, 1);                                       \
    ST2;                                                                       \
    WAITLG(); MFS(B, 1); RD(A, P, 1, 0);                                       \
    BARRIER(); ST3;                                                            \
    WAITLG(); MFS(A, 0); RD(B, P, 1, 1);                                       \
    ST4;                                                                       \
    WAITLG(); MFS(B, 1);                                                       \
    GATE; BARRIER();                                                           \
  } while (0)

// EPI 0: bf16 out split at n=8192 -> C0/C1 (gate+up).   EPI 1: bf16 3-way split at
// n=2048 -> C0/C1/C2 (QKV).   EPI 2: f32 split-K partial Cf + z*M*N, A/B offset z*Ktiles*64.
template <int EPI>
__global__ __launch_bounds__(512, 2) void gemm256(
    const unsigned short* __restrict__ A,
    const unsigned short* __restrict__ B,
    unsigned short* __restrict__ C0,
    unsigned short* __restrict__ C1,
    unsigned short* __restrict__ C2,
    float* __restrict__ Cf,
    int N, int kstr, int Ktiles) {
  // XCD-chunked block swizzle (bijective; all grids here are %8==0)
  const int gx = gridDim.x, gy = gridDim.y;
  const int nwg = gx * gy * gridDim.z;
  const int orig = blockIdx.x + gx * (blockIdx.y + gy * blockIdx.z);
  const int s = ((nwg & 7) == 0) ? ((orig & 7) * (nwg >> 3) + (orig >> 3)) : orig;
  const int bx = s % gx;
  const int sq = s / gx;
  const int by = sq % gy;
  const int bz = sq / gy;

  const int m0 = by * 256, n0 = bx * 256;
  const size_t koff = (size_t)bz * ((size_t)Ktiles * 64);

  const int t = threadIdx.x;
  const int lane = t & 63;
  const int w = t >> 6;
  const int quad = lane >> 4;
  const int l15 = lane & 15;
  const int wr = w >> 2;
  const int wc = w & 3;

  __shared__ __align__(16) unsigned short As[2][2][8192];
  __shared__ __align__(16) unsigned short Bs[2][2][8192];
  unsigned short* AsB = &As[0][0][0];
  unsigned short* BsB = &Bs[0][0][0];

  const f32x4 vzero = {0.f, 0.f, 0.f, 0.f};
  f32x4 acc[8][4];
#pragma unroll
  for (int i = 0; i < 8; ++i)
#pragma unroll
    for (int j = 0; j < 4; ++j) acc[i][j] = vzero;

  bf16x8 afrA[4], bfrA[4], afrB[4], bfrB[4];

  // ds_read swizzled unit offset (shorts): phys unit = quad ^ ((row>>1)&3), row ≡ l15 mod 16
  const int ko = (quad ^ ((l15 >> 1) & 3)) * 8;
  const unsigned short* aB = AsB + wr * 4096 + l15 * 32 + ko;   // wr*128 rows
  const unsigned short* bB = BsB + wc * 2048 + l15 * 32 + ko;   // wc*64 rows

  // staging source: thread covers row w*16+(lane>>2) (+128 for 2nd issue), unit lane&3;
  // source unit pre-swizzled so linear LDS dest lands swizzled
  const int usrc = (lane & 3) ^ ((lane >> 3) & 3);
  const unsigned short* pA =
      A + (size_t)(m0 + w * 16 + (lane >> 2)) * kstr + koff + usrc * 8;
  const unsigned short* pB =
      B + (size_t)(n0 + w * 16 + (lane >> 2)) * kstr + koff + usrc * 8;

  // prologue: 6 chunks [A0(0) B0(0) A1(0) B1(0) A0(1) B0(1)]; force tile0, leave 2
  STA(0, 0); STB(0, 0);
  STA(0, 1); STB(0, 1);
  STA(1, 0); STB(1, 0);
  WAITVM(4);
  BARRIER();

  const int pairs = (Ktiles - 2) >> 1;   // tiles 0..Ktiles-3 steady
  for (int it = 0; it < pairs; ++it) {
    TILE3(0, STA(1, 1), STB(1, 1), STA(0, 0), STB(0, 0), WAITVM(4));
    TILE3(1, STA(0, 1), STB(0, 1), STA(1, 0), STB(1, 0), WAITVM(4));
  }
  // tail: tile Kt-2 (buf0) stages last tile's ks1, drains everything
  TILE3(0, STA(1, 1), STB(1, 1), NOSTG, NOSTG, WAITVM(0));
  // tail: tile Kt-1 (buf1), all data resident
  TILE3(1, NOSTG, NOSTG, NOSTG, NOSTG, NOSTG);

  // ----- epilogue -----
  if constexpr (EPI == 2) {
    const size_t MN = (size_t)gy * 256 * N;
    float* Cp = Cf + (size_t)bz * MN;
#pragma unroll
    for (int mf = 0; mf < 8; ++mf) {
      const int m = m0 + wr * 128 + mf * 16 + quad * 4;
#pragma unroll
      for (int nf = 0; nf < 4; ++nf) {
        const int n = n0 + wc * 64 + nf * 16 + l15;
#pragma unroll
        for (int r = 0; r < 4; ++r) Cp[(size_t)(m + r) * N + n] = acc[mf][nf][r];
      }
    }
  } else {
    unsigned short* Cp;
    int nb;
    constexpr int ldc = (EPI == 0) ? 8192 : 2048;
    if constexpr (EPI == 0) {
      Cp = (n0 < 8192) ? C0 : C1;   // block-uniform (8192 % 256 == 0)
      nb = n0 & 8191;
    } else {
      const int wsel = n0 >> 11;    // block-uniform (2048 % 256 == 0)
      Cp = wsel == 0 ? C0 : (wsel == 1 ? C1 : C2);
      nb = n0 & 2047;
    }
#pragma unroll
    for (int mf = 0; mf < 8; ++mf) {
      const int m = m0 + wr * 128 + mf * 16 + quad * 4;
#pragma unroll
      for (int nf = 0; nf < 4; ++nf) {
        const int n = nb + wc * 64 + nf * 16 + l15;
#pragma unroll
        for (int r = 0; r < 4; ++r)
          Cp[(size_t)(m + r) * ldc + n] = f2b(acc[mf][nf][r]);
      }
    }
  }
}

// ---------------- silu(g)*u elementwise, in-place over g ----------------
__global__ __launch_bounds__(256) void silu_k(unsigned short* __restrict__ g,
                                              const unsigned short* __restrict__ u) {
  const size_t i = ((size_t)blockIdx.x * 256 + threadIdx.x) * 8;
  V16 gv, uv, ov;
  gv.u = *(const uint4*)(g + i);
  uv.u = *(const uint4*)(u + i);
#pragma unroll
  for (int e = 0; e < 8; ++e) {
    const float gf = b2f(gv.s[e]);
    const float uf = b2f(uv.s[e]);
    ov.s[e] = f2b(gf / (1.f + __expf(-gf)) * uf);
  }
  *(uint4*)(g + i) = ov.u;
}

// ---------------- split-K=4 combine: out = hf + p0+p1+p2+p3 ----------------
__global__ __launch_bounds__(256) void comb4(const float* __restrict__ p,
                                             const float* __restrict__ hf,
                                             float* __restrict__ out) {
  const size_t i = ((size_t)blockIdx.x * 256 + threadIdx.x) * 4;
  const size_t MN = (size_t)2048 * 2048;
  float4 a = *(const float4*)(p + i);
  const float4 b = *(const float4*)(p + MN + i);
  const float4 c = *(const float4*)(p + 2 * MN + i);
  const float4 d = *(const float4*)(p + 3 * MN + i);
  const float4 h = *(const float4*)(hf + i);
  a.x += b.x + c.x + d.x + h.x;
  a.y += b.y + c.y + d.y + h.y;
  a.z += b.z + c.z + d.z + h.z;
  a.w += b.w + c.w + d.w + h.w;
  *(float4*)(out + i) = a;
}

// ---------------- Flash W2 (Gaussian-kernel) attention ----------------
__global__ __launch_bounds__(256, 3) void flash_w2(
    const unsigned short* __restrict__ q,
    const unsigned short* __restrict__ kk,
    const unsigned short* __restrict__ v,
    const float* __restrict__ k2c,
    unsigned short* __restrict__ ctx) {
  constexpr int Cw = 2048;
  constexpr float TWOC = 0.08838834764831843f;  // 1/sqrt(128)
  const int h = blockIdx.y;
  const int i = (h >= 8) ? (31 - blockIdx.x) : blockIdx.x;
  const int i0 = i * 64;
  const int t = threadIdx.x;
  const int lane = t & 63;
  const int w = t >> 6;
  const int quad = lane >> 4;
  const int l15 = lane & 15;

  __shared__ __align__(16) unsigned short Ks[64 * 136];   // [j][d], pitch 136
  __shared__ __align__(16) unsigned short VTs[128 * 72];  // [d][j^], XOR-swizzled
  __shared__ __align__(16) unsigned short Ps[4][16 * 72]; // per-wave P

  bf16x8 aq[4];
  {
    const unsigned short* qp = q + (size_t)(i0 + w * 16 + l15) * Cw + h * 128;
#pragma unroll
    for (int kt = 0; kt < 4; ++kt) {
      V16 u;
      u.u = *(const uint4*)(qp + kt * 32 + quad * 8);
      aq[kt] = u.b;
    }
  }

  const f32x4 vzero = {0.f, 0.f, 0.f, 0.f};
  f32x4 o[8];
#pragma unroll
  for (int nt = 0; nt < 8; ++nt) o[nt] = vzero;
  float mrow[4] = {-1e30f, -1e30f, -1e30f, -1e30f};
  float lrow[4] = {0.f, 0.f, 0.f, 0.f};

  const int njt = i + 1;
  const int jr = t >> 2;
  const int c0 = (t & 3) * 32;
  const int jlo = jr & 7;
  const int jhi = jr >> 3;
  for (int jt = 0; jt < njt; ++jt) {
    const int j0 = jt * 64;
    __syncthreads();
    {
      const unsigned short* kp = kk + (size_t)(j0 + jr) * Cw + h * 128 + c0;
      const unsigned short* vp = v + (size_t)(j0 + jr) * Cw + h * 128 + c0;
#pragma unroll
      for (int ii = 0; ii < 4; ++ii) {
        *(uint4*)&Ks[jr * 136 + c0 + ii * 8] = *(const uint4*)(kp + ii * 8);
        V16 vu;
        vu.u = *(const uint4*)(vp + ii * 8);
#pragma unroll
        for (int e = 0; e < 8; ++e) {
          const int dd = c0 + ii * 8 + e;
          const int gs = (jhi ^ (dd >> 4)) & 7;
          VTs[dd * 72 + (jlo | (gs << 3))] = vu.s[e];
        }
      }
    }
    __syncthreads();

    float k2v[4];
#pragma unroll
    for (int ct = 0; ct < 4; ++ct) k2v[ct] = k2c[h * 2048 + j0 + ct * 16 + l15];

    f32x4 sc[4];
#pragma unroll
    for (int ct = 0; ct < 4; ++ct) {
      f32x4 a = vzero;
#pragma unroll
      for (int kt = 0; kt < 4; ++kt) {
        V16 u;
        u.u = *(const uint4*)&Ks[(ct * 16 + l15) * 136 + kt * 32 + quad * 8];
        a = mfma16(aq[kt], u.b, a);
      }
      sc[ct] = a;
    }

    const bool diag = (jt == njt - 1);
#pragma unroll
    for (int ct = 0; ct < 4; ++ct) {
#pragma unroll
      for (int r = 0; r < 4; ++r) {
        float s = fmaf(TWOC, sc[ct][r], -k2v[ct]);
        if (diag) {
          const int gi = w * 16 + quad * 4 + r;
          const int gj = ct * 16 + l15;
          s = (gj <= gi) ? s : -1e30f;
        }
        sc[ct][r] = s;
      }
    }

    float al[4];
#pragma unroll
    for (int r = 0; r < 4; ++r) {
      float rm = fmaxf(fmaxf(sc[0][r], sc[1][r]), fmaxf(sc[2][r], sc[3][r]));
      rm = fmaxf(rm, __shfl_xor(rm, 1));
      rm = fmaxf(rm, __shfl_xor(rm, 2));
      rm = fmaxf(rm, __shfl_xor(rm, 4));
      rm = fmaxf(rm, __shfl_xor(rm, 8));
      const float mn = fmaxf(mrow[r], rm);
      al[r] = __expf(mrow[r] - mn);
      mrow[r] = mn;
      float ps = 0.f;
#pragma unroll
      for (int ct = 0; ct < 4; ++ct) {
        const float p = __expf(sc[ct][r] - mn);
        sc[ct][r] = p;
        ps += p;
      }
      ps += __shfl_xor(ps, 1);
      ps += __shfl_xor(ps, 2);
      ps += __shfl_xor(ps, 4);
      ps += __shfl_xor(ps, 8);
      lrow[r] = lrow[r] * al[r] + ps;
    }
#pragma unroll
    for (int nt = 0; nt < 8; ++nt)
#pragma unroll
      for (int r = 0; r < 4; ++r) o[nt][r] *= al[r];

#pragma unroll
    for (int ct = 0; ct < 4; ++ct)
#pragma unroll
      for (int r = 0; r < 4; ++r)
        Ps[w][(quad * 4 + r) * 72 + ct * 16 + l15] = f2b(sc[ct][r]);

#pragma unroll
    for (int kt2 = 0; kt2 < 2; ++kt2) {
      V16 pa;
      pa.u = *(const uint4*)&Ps[w][l15 * 72 + kt2 * 32 + quad * 8];
#pragma unroll
      for (int nt = 0; nt < 8; ++nt) {
        V16 vb;
        const int dd = nt * 16 + l15;
        const int gs = (kt2 * 4 + quad) ^ nt;
        vb.u = *(const uint4*)&VTs[dd * 72 + gs * 8];
        o[nt] = mfma16(pa.b, vb.b, o[nt]);
      }
    }
  }

  float invl[4];
#pragma unroll
  for (int r = 0; r < 4; ++r) invl[r] = 1.f / lrow[r];
#pragma unroll
  for (int nt = 0; nt < 8; ++nt) {
#pragma unroll
    for (int r = 0; r < 4; ++r) {
      const int gi = i0 + w * 16 + quad * 4 + r;
      ctx[(size_t)gi * Cw + h * 128 + nt * 16 + l15] = f2b(o[nt][r] * invl[r]);
    }
  }
}

// ---------------- driver ----------------
extern "C" void kernel_launch(void* const* d_in, const int* in_sizes, int n_in,
                              void* d_out, int out_size, void* d_ws, size_t ws_size,
                              hipStream_t stream) {
  (void)in_sizes; (void)n_in; (void)out_size; (void)ws_size;
  const float* hid  = (const float*)d_in[0];
  const float* cosb = (const float*)d_in[1];
  const float* sinb = (const float*)d_in[2];
  // d_in[3] attention_mask: exactly causal -> applied analytically
  const float* ln1w = (const float*)d_in[4];
  const float* wq   = (const float*)d_in[5];
  const float* wk   = (const float*)d_in[6];
  const float* wv   = (const float*)d_in[7];
  const float* wo   = (const float*)d_in[8];
  const float* ln2w = (const float*)d_in[9];
  const float* wg   = (const float*)d_in[10];
  const float* wu   = (const float*)d_in[11];
  const float* wd   = (const float*)d_in[12];
  float* outp = (float*)d_out;

  const size_t SC = (size_t)2048 * 2048;       // 4.19M
  const size_t FC = (size_t)8192 * 2048;       // 16.78M
  unsigned short* p = (unsigned short*)d_ws;
  unsigned short* wqb = p;  p += SC;
  unsigned short* wkb = p;  p += SC;
  unsigned short* wvb = p;  p += SC;
  unsigned short* wob = p;  p += SC;
  unsigned short* wgb = p;  p += FC;
  unsigned short* wub = p;  p += FC;
  unsigned short* wdb = p;  p += FC;
  unsigned short* xn  = p;  p += SC;           // reused as yn
  unsigned short* qb  = p;  p += SC;
  unsigned short* kb  = p;  p += SC;
  unsigned short* vb  = p;  p += SC;
  unsigned short* ctxb = p; p += SC;
  float* hf = (float*)p;   p += 2 * SC;        // f32 h = hidden + attn_out
  float* k2cb = (float*)p;                     // [H][S] = k^2 * c
  unsigned short* yn = xn;                     // xn dead after QKV
  // region reuse after their producers/consumers retire:
  unsigned short* gate = wqb;                  // wq..wo (4*SC) dead after QKV-proj:
                                               //   gate half of gate+up, then fused act
  unsigned short* upb  = qb;                   // qb..ctxb (4*SC) dead after wo-proj:
                                               //   up half of gate+up
  float* pd = (float*)wgb;                     // wg+wu (2*FC shorts = 4*SC floats) dead
                                               //   after gate+up -> 4 down split-K partials

  // 0. all weights f32 -> bf16 (one launch; dst regions contiguous)
  cvt_all<<<65536, 256, 0, stream>>>(wq, wk, wv, wo, wg, wu, wd, wqb);

  // 1. input RMSNorm
  rms_k<<<2048, 256, 0, stream>>>(hid, ln1w, xn);
  // 2. fused QKV projection: single 256^2 GEMM over contiguous [wq;wk;wv] (N=6144)
  gemm256<1><<<dim3(24, 8, 1), 512, 0, stream>>>(xn, wqb, qb, kb, vb, nullptr,
                                                 6144, 2048, 32);
  // 3. RoPE in-place on q,k + k^2*c precompute
  rope_qk<<<8192, 256, 0, stream>>>(qb, kb, cosb, sinb, k2cb);
  // 4. W2 attention -> ctx
  flash_w2<<<dim3(32, 16), 256, 0, stream>>>(qb, kb, vb, k2cb, ctxb);
  // 5. output projection + residual -> h (f32)  (64 tiles only -> keep 128-wide kernel)
  gemm_nt<1, 2><<<dim3(16, 32, 1), 256, 0, stream>>>(ctxb, wob, wob, wob,
                                                     nullptr, nullptr, nullptr,
                                                     hid, hf, 2048, 2048, 2048);
  // 6. post-attn RMSNorm
  rms_k<<<2048, 256, 0, stream>>>(hf, ln2w, yn);
  // 7. gate+up: single 256^2 GEMM over contiguous [wg;wu] (N=16384)
  gemm256<0><<<dim3(64, 8, 1), 512, 0, stream>>>(yn, wgb, gate, upb, nullptr, nullptr,
                                                 16384, 2048, 32);
  // 8. silu(g)*u in-place over gate region
  silu_k<<<8192, 256, 0, stream>>>(gate, upb);
  // 9. down GEMM, split-K=4 -> f32 partials over dead wg/wu region
  gemm256<2><<<dim3(8, 8, 4), 512, 0, stream>>>(gate, wdb, nullptr, nullptr, nullptr,
                                                pd, 2048, 8192, 32);
  // 10. combine: out = hf + p0+p1+p2+p3
  comb4<<<4096, 256, 0, stream>>>(pd, hf, outp);
}